// Round 1
// baseline (359.325 us; speedup 1.0000x reference)
//
#include <hip/hip_runtime.h>
#include <math.h>

#define N_NODES 100000
#define N_EDGES 1200000
#define F_IN    64
#define F_HID   16
#define F_OUT   40

// ---------------------------------------------------------------- degree
__global__ void deg_kernel(const int* __restrict__ dst, float* __restrict__ deg, int nE) {
    int e = blockIdx.x * blockDim.x + threadIdx.x;
    if (e < nE) atomicAdd(&deg[dst[e]], 1.0f);
}

// ---------------------------------------------------------------- t1 = x @ W1_neigh  (N x 64) @ (64 x 16)
__global__ void xw_kernel(const float* __restrict__ x, const float* __restrict__ W,
                          float* __restrict__ t1, int n) {
    __shared__ float sW[F_IN][F_HID];
    int tid = threadIdx.x;                       // 256 threads
    for (int i = tid; i < F_IN * F_HID; i += 256) sW[i / F_HID][i % F_HID] = W[i];
    __syncthreads();
    int row = blockIdx.x * 16 + (tid >> 4);
    int col = tid & 15;
    if (row >= n) return;
    const float* xr = x + row * F_IN;
    float s = 0.f;
#pragma unroll
    for (int k = 0; k < F_IN; k++) s += xr[k] * sW[k][col];
    t1[row * F_HID + col] = s;
}

// ---------------------------------------------------------------- scatter: agg[dst] += t[src]  (16 floats/edge)
__global__ void scatter16_kernel(const int* __restrict__ src, const int* __restrict__ dst,
                                 const float* __restrict__ t, float* __restrict__ agg, int nE) {
    int tid = blockIdx.x * blockDim.x + threadIdx.x;
    int e = tid >> 4;
    int f = tid & 15;
    if (e >= nE) return;
    int s = src[e];
    int d = dst[e];
    atomicAdd(&agg[d * F_HID + f], t[s * F_HID + f]);
}

// ---------------------------------------------------------------- h = relu(x@W1_self + agg1/deg + b1)
__global__ void layer1_kernel(const float* __restrict__ x, const float* __restrict__ Wself,
                              const float* __restrict__ b1, const float* __restrict__ agg,
                              const float* __restrict__ deg, float* __restrict__ h, int n) {
    __shared__ float sW[F_IN][F_HID];
    __shared__ float sb[F_HID];
    int tid = threadIdx.x;
    for (int i = tid; i < F_IN * F_HID; i += 256) sW[i / F_HID][i % F_HID] = Wself[i];
    if (tid < F_HID) sb[tid] = b1[tid];
    __syncthreads();
    int row = blockIdx.x * 16 + (tid >> 4);
    int col = tid & 15;
    if (row >= n) return;
    const float* xr = x + row * F_IN;
    float s = sb[col];
#pragma unroll
    for (int k = 0; k < F_IN; k++) s += xr[k] * sW[k][col];
    float inv = 1.0f / fmaxf(deg[row], 1.0f);
    s += agg[row * F_HID + col] * inv;
    h[row * F_HID + col] = fmaxf(s, 0.0f);
}

// ---------------------------------------------------------------- out = logsoftmax(h@W2s + (agg2/deg)@W2n + b2)
// one wave (64 lanes) per row; lanes 0..39 each own one output class
__global__ void layer2_kernel(const float* __restrict__ h, const float* __restrict__ agg,
                              const float* __restrict__ deg,
                              const float* __restrict__ Wself, const float* __restrict__ Wneigh,
                              const float* __restrict__ b2, float* __restrict__ out, int n) {
    __shared__ float sWs[F_HID * F_OUT];
    __shared__ float sWn[F_HID * F_OUT];
    __shared__ float sb[F_OUT];
    int tid = threadIdx.x;                       // 256 = 4 waves
    for (int i = tid; i < F_HID * F_OUT; i += 256) { sWs[i] = Wself[i]; sWn[i] = Wneigh[i]; }
    if (tid < F_OUT) sb[tid] = b2[tid];
    __syncthreads();
    int row = blockIdx.x * 4 + (tid >> 6);
    int lane = tid & 63;
    if (row >= n) return;
    float inv = 1.0f / fmaxf(deg[row], 1.0f);
    float hrow[F_HID], arow[F_HID];
#pragma unroll
    for (int k = 0; k < F_HID; k++) {
        hrow[k] = h[row * F_HID + k];
        arow[k] = agg[row * F_HID + k] * inv;
    }
    int c = lane;
    float s = 0.0f;
    float v = -INFINITY;
    if (c < F_OUT) {
        s = sb[c];
#pragma unroll
        for (int k = 0; k < F_HID; k++)
            s += hrow[k] * sWs[k * F_OUT + c] + arow[k] * sWn[k * F_OUT + c];
        v = s;
    }
    // wave max
    float m = v;
#pragma unroll
    for (int off = 32; off; off >>= 1) m = fmaxf(m, __shfl_xor(m, off));
    float ex = (c < F_OUT) ? __expf(s - m) : 0.0f;
    float sum = ex;
#pragma unroll
    for (int off = 32; off; off >>= 1) sum += __shfl_xor(sum, off);
    if (c < F_OUT) out[row * F_OUT + c] = s - m - __logf(sum);
}

extern "C" void kernel_launch(void* const* d_in, const int* in_sizes, int n_in,
                              void* d_out, int out_size, void* d_ws, size_t ws_size,
                              hipStream_t stream) {
    const float* x       = (const float*)d_in[0];
    const int*   edges   = (const int*)d_in[1];   // (2, N_EDGES) row-major
    const float* W1_self = (const float*)d_in[2];
    const float* W1_neigh= (const float*)d_in[3];
    const float* b1      = (const float*)d_in[4];
    const float* W2_self = (const float*)d_in[5];
    const float* W2_neigh= (const float*)d_in[6];
    const float* b2      = (const float*)d_in[7];
    float* out = (float*)d_out;

    const int* src = edges;
    const int* dst = edges + N_EDGES;

    // workspace layout (floats): deg[N] | buf[16N] (t1, reused as h) | agg[16N] (agg1, reused as agg2)
    float* deg  = (float*)d_ws;
    float* buf  = deg + N_NODES;          // t1, then h
    float* agg  = buf + 16 * N_NODES;     // agg1, then agg2

    const int B = 256;

    // zero deg + agg1
    hipMemsetAsync(deg, 0, N_NODES * sizeof(float), stream);
    hipMemsetAsync(agg, 0, 16 * N_NODES * sizeof(float), stream);

    deg_kernel<<<(N_EDGES + B - 1) / B, B, 0, stream>>>(dst, deg, N_EDGES);
    xw_kernel<<<(N_NODES + 15) / 16, B, 0, stream>>>(x, W1_neigh, buf, N_NODES);
    scatter16_kernel<<<(N_EDGES * 16 + B - 1) / B, B, 0, stream>>>(src, dst, buf, agg, N_EDGES);
    layer1_kernel<<<(N_NODES + 15) / 16, B, 0, stream>>>(x, W1_self, b1, agg, deg, buf, N_NODES);

    // re-zero agg for layer 2
    hipMemsetAsync(agg, 0, 16 * N_NODES * sizeof(float), stream);
    scatter16_kernel<<<(N_EDGES * 16 + B - 1) / B, B, 0, stream>>>(src, dst, buf, agg, N_EDGES);
    layer2_kernel<<<(N_NODES + 3) / 4, B, 0, stream>>>(buf, agg, deg, W2_self, W2_neigh, b2,
                                                       out, N_NODES);
}